// Round 12
// baseline (35.419 us; speedup 1.0000x reference)
//
#include <hip/hip_runtime.h>
#include <math.h>

#define BP  1024   // pair blocks
#define BR  1024   // reducer blocks   (total 2048 = 8/CU, all resident)
#define TPB 256

__device__ __forceinline__ float waveReduceSum(float v) {
    #pragma unroll
    for (int off = 32; off > 0; off >>= 1)
        v += __shfl_down(v, off, 64);
    return v;
}

#define CONS(AV, PV, S) { float d_;                       \
    d_ = (AV).x - (PV).x; S += d_ * d_;                   \
    d_ = (AV).y - (PV).y; S += d_ * d_;                   \
    d_ = (AV).z - (PV).z; S += d_ * d_;                   \
    d_ = (AV).w - (PV).w; S += d_ * d_; }

#define RCONS(V, S) { float r_;                           \
    r_ = fmaxf((V).x, 0.f); S += r_ * r_;                 \
    r_ = fmaxf((V).y, 0.f); S += r_ * r_;                 \
    r_ = fmaxf((V).z, 0.f); S += r_ * r_;                 \
    r_ = fmaxf((V).w, 0.f); S += r_ * r_; }

// ws layout (floats): [0,BR) s0 partials ; [BR,2BR) s1 partials ; [2BR,2BR+BP) pair partials
__global__ __launch_bounds__(TPB, 8)
void fused_kernel(const float* __restrict__ a,
                  const float* __restrict__ p,
                  const float* __restrict__ Pm,
                  const float* __restrict__ S,
                  const int* __restrict__ ii,
                  const int* __restrict__ jj,
                  float* __restrict__ ws,
                  long nAP, long nP, int Npair, int D, int K)
{
    __shared__ float sm0[4], sm1[4];
    const int wave = threadIdx.x >> 6;
    const int lane = threadIdx.x & 63;
    const int bid  = blockIdx.x;

    if (bid < BP) {
        // ---- pair role: VERBATIM R8 (16 pairs/block, 4/wave, Si hoisted) ----
        const int totalPairs = Npair * Npair;
        const int base = bid * 16 + wave * 4;
        float local = 0.f;

        if (base < totalPairs && D == 1024 && (base % Npair) + 3 < Npair) {
            const int ig = base / Npair;
            const int j0 = base - ig * Npair;
            const int ri = ii[ig];
            const float4* Si4 = (const float4*)(S + (long)ri * D);
            float4 x0 = Si4[lane];
            float4 x1 = Si4[lane + 64];
            float4 x2 = Si4[lane + 128];
            float4 x3 = Si4[lane + 192];
            const long riK = (long)ri * K;

            float d2q[4];
            int   rjq[4];
            #pragma unroll
            for (int q = 0; q < 4; ++q) {
                const int rj = jj[j0 + q];
                rjq[q] = rj;
                const float4* Sj4 = (const float4*)(S + (long)rj * D);
                float4 y0 = Sj4[lane];
                float4 y1 = Sj4[lane + 64];
                float4 y2 = Sj4[lane + 128];
                float4 y3 = Sj4[lane + 192];
                float d2 = 0.f, e;
                e = x0.x - y0.x; d2 += e * e;
                e = x0.y - y0.y; d2 += e * e;
                e = x0.z - y0.z; d2 += e * e;
                e = x0.w - y0.w; d2 += e * e;
                e = x1.x - y1.x; d2 += e * e;
                e = x1.y - y1.y; d2 += e * e;
                e = x1.z - y1.z; d2 += e * e;
                e = x1.w - y1.w; d2 += e * e;
                e = x2.x - y2.x; d2 += e * e;
                e = x2.y - y2.y; d2 += e * e;
                e = x2.z - y2.z; d2 += e * e;
                e = x2.w - y2.w; d2 += e * e;
                e = x3.x - y3.x; d2 += e * e;
                e = x3.y - y3.y; d2 += e * e;
                e = x3.z - y3.z; d2 += e * e;
                e = x3.w - y3.w; d2 += e * e;
                d2q[q] = d2;
            }
            #pragma unroll
            for (int q = 0; q < 4; ++q)
                d2q[q] = waveReduceSum(d2q[q]);
            if (lane == 0) {
                #pragma unroll
                for (int q = 0; q < 4; ++q)
                    if (d2q[q] > 0.f)
                        local += fmaxf(Pm[riK + rjq[q]], 0.f) * sqrtf(d2q[q]);
            }
        } else {
            // generic fallback
            #pragma unroll
            for (int q = 0; q < 4; ++q) {
                int pair = base + q;
                if (pair < totalPairs) {
                    int ig = pair / Npair;
                    int j  = pair - ig * Npair;
                    int ri = ii[ig];
                    int rj = jj[j];
                    const float* Si = S + (long)ri * D;
                    const float* Sj = S + (long)rj * D;
                    float d2 = 0.f;
                    for (int c = lane; c < D; c += 64) {
                        float e = Si[c] - Sj[c];
                        d2 += e * e;
                    }
                    d2 = waveReduceSum(d2);
                    if (lane == 0 && d2 > 0.f)
                        local += fmaxf(Pm[(long)ri * K + rj], 0.f) * sqrtf(d2);
                }
            }
        }
        if (lane == 0) sm0[wave] = local;
        __syncthreads();
        if (threadIdx.x == 0)
            ws[2 * BR + bid] = sm0[0] + sm0[1] + sm0[2] + sm0[3];
    } else {
        // ---- reducer role: R11's software-pipelined stream, 2x TLP ----
        const int  rb     = bid - BP;
        const long tid    = (long)rb * TPB + threadIdx.x;
        const long stride = (long)BR * TPB;           // 262,144 threads

        const float4* a4 = (const float4*)a;
        const float4* p4 = (const float4*)p;
        const long n4  = nAP >> 2;                    // 4,194,304 -> 16/thread = 4 batches
        const long nP4 = nP  >> 2;                    // 1,048,576 -> 4/thread  = 1 batch

        float s0a = 0.f, s0b = 0.f, s0c = 0.f, s0d = 0.f;

        if (n4 == 16L * stride) {
            float4 A[2][4], Pv[2][4];
            long i = tid;
            #pragma unroll
            for (int u = 0; u < 4; ++u) {
                A[0][u]  = a4[i + u * stride];
                Pv[0][u] = p4[i + u * stride];
            }
            i += 4 * stride;
            #pragma unroll
            for (int it = 1; it < 4; ++it) {          // fully unrolled, constant indices
                const int nxt = it & 1;
                const int cur = nxt ^ 1;
                #pragma unroll
                for (int u = 0; u < 4; ++u) {
                    A[nxt][u]  = a4[i + u * stride];
                    Pv[nxt][u] = p4[i + u * stride];
                }
                i += 4 * stride;
                __builtin_amdgcn_sched_barrier(0);    // prefetch stays above consume
                CONS(A[cur][0], Pv[cur][0], s0a);
                CONS(A[cur][1], Pv[cur][1], s0b);
                CONS(A[cur][2], Pv[cur][2], s0c);
                CONS(A[cur][3], Pv[cur][3], s0d);
            }
            CONS(A[1][0], Pv[1][0], s0a);             // last batch lives in buffer 1
            CONS(A[1][1], Pv[1][1], s0b);
            CONS(A[1][2], Pv[1][2], s0c);
            CONS(A[1][3], Pv[1][3], s0d);
        } else {
            for (long i = tid; i < n4; i += stride) {
                float4 av = a4[i], pv = p4[i];
                CONS(av, pv, s0a);
            }
        }

        const float4* P4 = (const float4*)Pm;
        float s1a = 0.f, s1b = 0.f;
        if (nP4 == 4L * stride) {
            float4 B0 = P4[tid];
            float4 B1 = P4[tid + stride];
            float4 B2 = P4[tid + 2 * stride];
            float4 B3 = P4[tid + 3 * stride];
            __builtin_amdgcn_sched_barrier(0);
            RCONS(B0, s1a); RCONS(B1, s1b);
            RCONS(B2, s1a); RCONS(B3, s1b);
        } else {
            for (long q = tid; q < nP4; q += stride) {
                float4 v = P4[q];
                RCONS(v, s1a);
            }
        }

        float s0 = waveReduceSum(s0a + s0b + s0c + s0d);
        float s1 = waveReduceSum(s1a + s1b);
        if (lane == 0) { sm0[wave] = s0; sm1[wave] = s1; }
        __syncthreads();
        if (threadIdx.x == 0) {
            ws[rb]      = sm0[0] + sm0[1] + sm0[2] + sm0[3];
            ws[BR + rb] = sm1[0] + sm1[1] + sm1[2] + sm1[3];
        }
    }
}

__global__ void finalize_kernel(const float* __restrict__ ws,
                                const float* __restrict__ lamb,
                                float* __restrict__ out)
{
    float a0 = 0.f, a1 = 0.f, a2 = 0.f;
    for (int i = threadIdx.x; i < BR; i += TPB) {
        a0 += ws[i];
        a1 += ws[BR + i];
    }
    for (int i = threadIdx.x; i < BP; i += TPB)
        a2 += ws[2 * BR + i];

    a0 = waveReduceSum(a0);
    a1 = waveReduceSum(a1);
    a2 = waveReduceSum(a2);

    __shared__ float m0[4], m1[4], m2[4];
    int wave = threadIdx.x >> 6;
    int lane = threadIdx.x & 63;
    if (lane == 0) { m0[wave] = a0; m1[wave] = a1; m2[wave] = a2; }
    __syncthreads();
    if (threadIdx.x == 0) {
        float A0 = m0[0] + m0[1] + m0[2] + m0[3];
        float A1 = m1[0] + m1[1] + m1[2] + m1[3];
        float A2 = m2[0] + m2[1] + m2[2] + m2[3];
        out[0] = sqrtf(A0) + lamb[0] * (sqrtf(A1) + A2);
    }
}

extern "C" void kernel_launch(void* const* d_in, const int* in_sizes, int n_in,
                              void* d_out, int out_size, void* d_ws, size_t ws_size,
                              hipStream_t stream) {
    const float* actual = (const float*)d_in[0];
    const float* pred   = (const float*)d_in[1];
    const float* lamb   = (const float*)d_in[2];
    const float* Pm     = (const float*)d_in[3];
    const float* S      = (const float*)d_in[4];
    const int*   ii     = (const int*)d_in[5];
    const int*   jj     = (const int*)d_in[6];
    float* out = (float*)d_out;
    float* ws  = (float*)d_ws;

    long nAP   = in_sizes[0];                       // 4096*4096
    long nP    = in_sizes[3];                       // 2048*2048
    int  K     = (int)lround(sqrt((double)nP));     // 2048
    int  Npair = in_sizes[5];                       // 128
    int  D     = (int)(in_sizes[4] / K);            // 1024

    fused_kernel<<<BP + BR, TPB, 0, stream>>>(actual, pred, Pm, S, ii, jj, ws,
                                              nAP, nP, Npair, D, K);
    finalize_kernel<<<1, TPB, 0, stream>>>(ws, lamb, out);
}